// Round 3
// baseline (801.357 us; speedup 1.0000x reference)
//
#include <hip/hip_runtime.h>
#include <hip/hip_bf16.h>

#define NN 100000
#define NE 3200000
#define DI 128
#define DH 16
#define NB 391            // buckets of 256 nodes: ceil(NN/256)
#define BCAP 10240        // pair slots per bucket (E[count]=8192, +22 sigma)
#define EPB 8192          // edges per bin block
#define NBIN_BLK 391      // ceil(NE/EPB)

// ws layout (need 23,355,392 B = 22.3 MiB; round-1 pass proved >= 23.1 MiB usable):
//   0        flag (4B)
//   1024     gcursor[NB+1] (uint)
//   65536    dinv[NN] (400 KB)
//   524288   g[NN*16] f32 (6.4 MB)
//   7340032  pairs[NB*BCAP] uint (16.0 MB)
// h1 lives in d_out.

// edge index may be int32 or int64 (JAX x64 flag unknown); detect at runtime.
__global__ __launch_bounds__(256) void detect_kernel(const unsigned int* __restrict__ w,
                                                     unsigned int* __restrict__ flag) {
    unsigned int v = 0;
    for (int i = threadIdx.x; i < 4096; i += 256) v |= w[2 * i + 1];
    if (v) atomicOr(flag, 1u);  // nonzero odd words => int32 layout
}

__global__ __launch_bounds__(256) void init_kernel(unsigned int* __restrict__ flag,
                                                   unsigned int* __restrict__ gcursor) {
    int t = blockIdx.x * 256 + threadIdx.x;
    if (t == 0) *flag = 0u;
    if (t < NB) gcursor[t] = (unsigned int)t * BCAP;
}

// Bucketed counting sort: 8192 edges/block -> LDS sort by dst>>8 -> run-contiguous
// (mostly coalesced) copy-out into per-bucket global regions.
__global__ __launch_bounds__(256) void bin_kernel(const int* __restrict__ ew,
                                                  const unsigned int* __restrict__ flag,
                                                  unsigned int* __restrict__ gcursor,
                                                  unsigned int* __restrict__ pairs) {
    __shared__ unsigned int hist[NB + 1];    // 392 (last padded 0)
    __shared__ unsigned int lbase[NB + 1];   // exclusive scan; lbase[NB] = total
    __shared__ unsigned int lcur[NB];
    __shared__ unsigned int gbase[NB];
    __shared__ unsigned int ps[256];
    __shared__ unsigned int sorted[EPB];     // 32 KB

    int tid = threadIdx.x;
    int is32 = (*flag != 0);
    int e0 = blockIdx.x * EPB;

    for (int b = tid; b < NB + 1; b += 256) hist[b] = 0;
    __syncthreads();

    int dd[32], ss[32];
    unsigned int valid = 0;
#pragma unroll
    for (int k = 0; k < 32; ++k) {
        int e = e0 + tid + k * 256;
        int d = 0, s = 0;
        if (e < NE) {
            s = is32 ? ew[e] : ew[2 * e];
            d = is32 ? ew[NE + e] : ew[2 * (NE + e)];
            if ((unsigned)s < NN && (unsigned)d < NN) {
                valid |= (1u << k);
                atomicAdd(&hist[d >> 8], 1u);
            }
        }
        dd[k] = d; ss[k] = s;
    }
    __syncthreads();

    // scan 392 entries as 196 pairs with Hillis-Steele over ps[256]
    unsigned int psum = 0;
    if (tid < 196) { psum = hist[2 * tid] + hist[2 * tid + 1]; ps[tid] = psum; }
    else ps[tid] = 0;
    __syncthreads();
    for (int o = 1; o < 256; o <<= 1) {
        unsigned int v = (tid >= o) ? ps[tid - o] : 0;
        __syncthreads();
        ps[tid] += v;
        __syncthreads();
    }
    if (tid < 196) {
        unsigned int eb = ps[tid] - psum;       // exclusive base of pair
        lbase[2 * tid] = eb;
        lbase[2 * tid + 1] = eb + hist[2 * tid];  // t=195 also writes lbase[391]=total
    }
    __syncthreads();

    for (int b = tid; b < NB; b += 256) {
        lcur[b] = lbase[b];
        unsigned int c = hist[b];
        gbase[b] = (c > 0) ? atomicAdd(&gcursor[b], c) : 0u;
    }
    __syncthreads();

#pragma unroll
    for (int k = 0; k < 32; ++k) {
        if (valid & (1u << k)) {
            int b = dd[k] >> 8;
            unsigned int pos = atomicAdd(&lcur[b], 1u);
            sorted[pos] = ((unsigned int)ss[k] << 8) | ((unsigned int)dd[k] & 255u);
        }
    }
    __syncthreads();

    unsigned int total = lbase[NB];
    for (unsigned int i = tid; i < total; i += 256) {
        int lo = 0, hi = NB;                 // find b: lbase[b] <= i < lbase[b+1]
        while (hi - lo > 1) {
            int mid = (lo + hi) >> 1;
            if (lbase[mid] <= i) lo = mid; else hi = mid;
        }
        unsigned int gp = gbase[lo] + (i - lbase[lo]);
        if (gp < (unsigned int)(lo + 1) * BCAP)  // overflow insurance
            pairs[gp] = sorted[i];
    }
}

// deg (from binned pairs) -> dinv = rsqrt(indeg + 1)
__global__ __launch_bounds__(256) void degdinv_kernel(const unsigned int* __restrict__ pairs,
                                                      const unsigned int* __restrict__ gcursor,
                                                      float* __restrict__ dinv) {
    __shared__ unsigned int cnt[256];
    int b = blockIdx.x, tid = threadIdx.x;
    cnt[tid] = 0;
    __syncthreads();
    unsigned int start = (unsigned int)b * BCAP, end = gcursor[b];
    for (unsigned int i = start + tid; i < end; i += 256)
        atomicAdd(&cnt[pairs[i] & 255u], 1u);
    __syncthreads();
    int v = b * 256 + tid;
    if (v < NN) dinv[v] = rsqrtf((float)(cnt[tid] + 1u));
}

// g1[v][j] = (x[v] . W1[:,j]) * dinv[v]
__global__ __launch_bounds__(256) void gemm1_kernel(const float* __restrict__ x,
                                                    const float* __restrict__ W1,
                                                    const float* __restrict__ dinv,
                                                    float* __restrict__ g) {
    __shared__ float wl[DI * DH];
    __shared__ float xs[16 * 132];
    int tid = threadIdx.x;
    int n0 = blockIdx.x * 16;
    for (int i = tid; i < 512; i += 256)
        ((float4*)wl)[i] = ((const float4*)W1)[i];
    for (int i = tid; i < 512; i += 256) {
        int ln = i >> 5;
        int k4 = (i & 31) << 2;
        *(float4*)&xs[ln * 132 + k4] =
            *(const float4*)&x[(size_t)(n0 + ln) * DI + k4];
    }
    __syncthreads();
    int ln = tid >> 4, j = tid & 15;
    int v = n0 + ln;
    float acc = 0.f;
#pragma unroll
    for (int k = 0; k < DI; ++k)
        acc += xs[ln * 132 + k] * wl[k * 16 + j];
    g[v * 16 + j] = acc * dinv[v];
}

// per-bucket LDS-accumulate propagation + fused finalize:
// out[v][f] = tanh(dinv[v]*(g[v][f] + sum_{e:dst=v} g[src][f]) + bias[f])
__global__ __launch_bounds__(512) void prop_kernel(const unsigned int* __restrict__ pairs,
                                                   const unsigned int* __restrict__ gcursor,
                                                   const float* __restrict__ g,
                                                   const float* __restrict__ dinv,
                                                   const float* __restrict__ bias,
                                                   float* __restrict__ out) {
    __shared__ float acc[256 * 16];        // 16 KB
    __shared__ unsigned int stage[512];
    int b = blockIdx.x, tid = threadIdx.x;
    for (int i = tid; i < 4096; i += 512) acc[i] = 0.f;
    __syncthreads();
    unsigned int start = (unsigned int)b * BCAP, end = gcursor[b];
    int f = tid & 15;
    for (unsigned int c = start; c < end; c += 512) {
        unsigned int n = min(512u, end - c);
        if ((unsigned int)tid < n) stage[tid] = pairs[c + tid];
        __syncthreads();
        for (int it = 0; it < 16; ++it) {
            unsigned int j = it * 32 + (tid >> 4);
            if (j < n) {
                unsigned int p = stage[j];
                int s = p >> 8;
                int d = p & 255;
                atomicAdd(&acc[d * 16 + f], g[s * 16 + f]);  // LDS atomic
            }
        }
        __syncthreads();
    }
    int n0 = b * 256;
    for (int idx = tid; idx < 4096; idx += 512) {
        int v = n0 + (idx >> 4);
        if (v < NN) {
            int ff = idx & 15;
            float sum = acc[idx] + g[v * 16 + ff];  // + self loop
            out[v * 16 + ff] = tanhf(dinv[v] * sum + bias[ff]);
        }
    }
}

// g2[v][j] = (h1[v] . W2[:,j]) * dinv[v]
__global__ __launch_bounds__(256) void gemm2_kernel(const float* __restrict__ h1,
                                                    const float* __restrict__ dinv,
                                                    const float* __restrict__ W2,
                                                    float* __restrict__ g2) {
    __shared__ float w2l[16 * 16];
    __shared__ float ht[16 * 17];
    int tid = threadIdx.x;
    w2l[tid] = W2[tid];
    int n0 = blockIdx.x * 16;
    int ln = tid >> 4, j = tid & 15;
    int v = n0 + ln;
    ht[ln * 17 + j] = h1[v * 16 + j];
    __syncthreads();
    float a = 0.f;
#pragma unroll
    for (int k = 0; k < 16; ++k)
        a += ht[ln * 17 + k] * w2l[k * 16 + j];
    g2[v * 16 + j] = a * dinv[v];
}

extern "C" void kernel_launch(void* const* d_in, const int* in_sizes, int n_in,
                              void* d_out, int out_size, void* d_ws, size_t ws_size,
                              hipStream_t stream) {
    const float* x  = (const float*)d_in[0];
    const int*   ew = (const int*)d_in[1];
    const float* W1 = (const float*)d_in[2];
    const float* b1 = (const float*)d_in[3];
    const float* W2 = (const float*)d_in[4];
    const float* b2 = (const float*)d_in[5];
    float* out = (float*)d_out;
    char* ws = (char*)d_ws;

    unsigned int* flag    = (unsigned int*)(ws);
    unsigned int* gcursor = (unsigned int*)(ws + 1024);
    float* dinv = (float*)(ws + 65536);
    float* g    = (float*)(ws + 524288);
    unsigned int* pairs = (unsigned int*)(ws + 7340032);
    float* h1 = out;  // reuse d_out as the h1 buffer (rewritten by final prop)

    init_kernel<<<2, 256, 0, stream>>>(flag, gcursor);
    detect_kernel<<<1, 256, 0, stream>>>((const unsigned int*)ew, flag);
    bin_kernel<<<NBIN_BLK, 256, 0, stream>>>(ew, flag, gcursor, pairs);
    degdinv_kernel<<<NB, 256, 0, stream>>>(pairs, gcursor, dinv);
    gemm1_kernel<<<NN / 16, 256, 0, stream>>>(x, W1, dinv, g);
    prop_kernel<<<NB, 512, 0, stream>>>(pairs, gcursor, g, dinv, b1, h1);
    gemm2_kernel<<<NN / 16, 256, 0, stream>>>(h1, dinv, W2, g);
    prop_kernel<<<NB, 512, 0, stream>>>(pairs, gcursor, g, dinv, b2, out);
}

// Round 4
// 783.606 us; speedup vs baseline: 1.0227x; 1.0227x over previous
//
#include <hip/hip_runtime.h>
#include <hip/hip_bf16.h>

#define NN 100000
#define NE 3200000
#define DI 128
#define DH 16
#define NB 391            // buckets of 256 nodes: ceil(NN/256)
#define BCAP 10240        // pair slots per bucket (E[count]=8192, +22 sigma)
#define EPB 8192          // edges per bin block
#define NBIN_BLK 391      // ceil(NE/EPB)

// ws layout (need 23,355,392 B = 22.3 MiB; round-2 CSR path proved >= 27.2 MiB):
//   0        flag (4B)
//   1024     gcursor[NB+1]
//   65536    dinv[NN] (400 KB)
//   524288   g[NN*16] f32 (6.4 MB)
//   7340032  pairs[NB*BCAP] uint (16.0 MB)
// h1 lives in d_out.

__global__ __launch_bounds__(256) void detect_kernel(const unsigned int* __restrict__ w,
                                                     unsigned int* __restrict__ flag) {
    unsigned int v = 0;
    for (int i = threadIdx.x; i < 4096; i += 256) v |= w[2 * i + 1];
    if (v) atomicOr(flag, 1u);  // nonzero odd words => int32 layout
}

__global__ __launch_bounds__(256) void init_kernel(unsigned int* __restrict__ flag,
                                                   unsigned int* __restrict__ gcursor) {
    int t = blockIdx.x * 256 + threadIdx.x;
    if (t == 0) *flag = 0u;
    if (t < NB) gcursor[t] = (unsigned int)t * BCAP;
}

// Bucketed counting sort: 8192 edges/block -> LDS sort by dst>>8 -> run-contiguous
// copy-out into per-bucket global regions.
__global__ __launch_bounds__(256) void bin_kernel(const int* __restrict__ ew,
                                                  const unsigned int* __restrict__ flag,
                                                  unsigned int* __restrict__ gcursor,
                                                  unsigned int* __restrict__ pairs) {
    __shared__ unsigned int hist[NB + 1];
    __shared__ unsigned int lbase[NB + 1];
    __shared__ unsigned int lcur[NB];
    __shared__ unsigned int gbase[NB];
    __shared__ unsigned int ps[256];
    __shared__ unsigned int sorted[EPB];     // 32 KB

    int tid = threadIdx.x;
    int is32 = (*flag != 0);
    int e0 = blockIdx.x * EPB;

    for (int b = tid; b < NB + 1; b += 256) hist[b] = 0;
    __syncthreads();

    int dd[32], ss[32];
    unsigned int valid = 0;
#pragma unroll
    for (int k = 0; k < 32; ++k) {
        int e = e0 + tid + k * 256;
        int d = 0, s = 0;
        if (e < NE) {
            s = is32 ? ew[e] : ew[2 * e];
            d = is32 ? ew[NE + e] : ew[2 * (NE + e)];
            if ((unsigned)s < NN && (unsigned)d < NN) {
                valid |= (1u << k);
                atomicAdd(&hist[d >> 8], 1u);
            }
        }
        dd[k] = d; ss[k] = s;
    }
    __syncthreads();

    // scan 392 entries as 196 pairs with Hillis-Steele over ps[256]
    unsigned int psum = 0;
    if (tid < 196) { psum = hist[2 * tid] + hist[2 * tid + 1]; ps[tid] = psum; }
    else ps[tid] = 0;
    __syncthreads();
    for (int o = 1; o < 256; o <<= 1) {
        unsigned int v = (tid >= o) ? ps[tid - o] : 0;
        __syncthreads();
        ps[tid] += v;
        __syncthreads();
    }
    if (tid < 196) {
        unsigned int eb = ps[tid] - psum;
        lbase[2 * tid] = eb;
        lbase[2 * tid + 1] = eb + hist[2 * tid];
    }
    __syncthreads();

    for (int b = tid; b < NB; b += 256) {
        lcur[b] = lbase[b];
        unsigned int c = hist[b];
        gbase[b] = (c > 0) ? atomicAdd(&gcursor[b], c) : 0u;
    }
    __syncthreads();

#pragma unroll
    for (int k = 0; k < 32; ++k) {
        if (valid & (1u << k)) {
            int b = dd[k] >> 8;
            unsigned int pos = atomicAdd(&lcur[b], 1u);
            sorted[pos] = ((unsigned int)ss[k] << 8) | ((unsigned int)dd[k] & 255u);
        }
    }
    __syncthreads();

    unsigned int total = lbase[NB];
    for (unsigned int i = tid; i < total; i += 256) {
        int lo = 0, hi = NB;
        while (hi - lo > 1) {
            int mid = (lo + hi) >> 1;
            if (lbase[mid] <= i) lo = mid; else hi = mid;
        }
        unsigned int gp = gbase[lo] + (i - lbase[lo]);
        if (gp < (unsigned int)(lo + 1) * BCAP)
            pairs[gp] = sorted[i];
    }
}

// deg (from binned pairs) -> dinv = rsqrt(indeg + 1)
__global__ __launch_bounds__(256) void degdinv_kernel(const unsigned int* __restrict__ pairs,
                                                      const unsigned int* __restrict__ gcursor,
                                                      float* __restrict__ dinv) {
    __shared__ unsigned int cnt[256];
    int b = blockIdx.x, tid = threadIdx.x;
    cnt[tid] = 0;
    __syncthreads();
    unsigned int start = (unsigned int)b * BCAP;
    unsigned int end = min(gcursor[b], start + BCAP);
    for (unsigned int i = start + tid; i < end; i += 256)
        atomicAdd(&cnt[pairs[i] & 255u], 1u);
    __syncthreads();
    int v = b * 256 + tid;
    if (v < NN) dinv[v] = rsqrtf((float)(cnt[tid] + 1u));
}

// g1[v][j] = (x[v] . W1[:,j]) * dinv[v]
__global__ __launch_bounds__(256) void gemm1_kernel(const float* __restrict__ x,
                                                    const float* __restrict__ W1,
                                                    const float* __restrict__ dinv,
                                                    float* __restrict__ g) {
    __shared__ float wl[DI * DH];
    __shared__ float xs[16 * 132];
    int tid = threadIdx.x;
    int n0 = blockIdx.x * 16;
    for (int i = tid; i < 512; i += 256)
        ((float4*)wl)[i] = ((const float4*)W1)[i];
    for (int i = tid; i < 512; i += 256) {
        int ln = i >> 5;
        int k4 = (i & 31) << 2;
        *(float4*)&xs[ln * 132 + k4] =
            *(const float4*)&x[(size_t)(n0 + ln) * DI + k4];
    }
    __syncthreads();
    int ln = tid >> 4, j = tid & 15;
    int v = n0 + ln;
    float acc = 0.f;
#pragma unroll
    for (int k = 0; k < DI; ++k)
        acc += xs[ln * 132 + k] * wl[k * 16 + j];
    g[v * 16 + j] = acc * dinv[v];
}

// One pair per thread: coalesced pair read, one 64-B g-row gather, 16
// independent LDS atomics (16 distinct banks). No barriers in the pair loop.
__global__ __launch_bounds__(1024) void prop_kernel(const unsigned int* __restrict__ pairs,
                                                    const unsigned int* __restrict__ gcursor,
                                                    const float* __restrict__ g,
                                                    const float* __restrict__ dinv,
                                                    const float* __restrict__ bias,
                                                    float* __restrict__ out) {
    __shared__ float acc[256 * 16];        // 16 KB
    int b = blockIdx.x, tid = threadIdx.x;
    for (int i = tid; i < 4096; i += 1024) acc[i] = 0.f;
    __syncthreads();
    unsigned int start = (unsigned int)b * BCAP;
    unsigned int end = min(gcursor[b], start + BCAP);
    for (unsigned int i = start + tid; i < end; i += 1024) {
        unsigned int p = pairs[i];
        int s = p >> 8;
        int d = p & 255;
        const float4* gr = (const float4*)&g[s * 16];
        float4 a0 = gr[0], a1 = gr[1], a2 = gr[2], a3 = gr[3];
        float* ac = &acc[d * 16];
        atomicAdd(&ac[0],  a0.x); atomicAdd(&ac[1],  a0.y);
        atomicAdd(&ac[2],  a0.z); atomicAdd(&ac[3],  a0.w);
        atomicAdd(&ac[4],  a1.x); atomicAdd(&ac[5],  a1.y);
        atomicAdd(&ac[6],  a1.z); atomicAdd(&ac[7],  a1.w);
        atomicAdd(&ac[8],  a2.x); atomicAdd(&ac[9],  a2.y);
        atomicAdd(&ac[10], a2.z); atomicAdd(&ac[11], a2.w);
        atomicAdd(&ac[12], a3.x); atomicAdd(&ac[13], a3.y);
        atomicAdd(&ac[14], a3.z); atomicAdd(&ac[15], a3.w);
    }
    __syncthreads();
    int n0 = b * 256;
    for (int idx = tid; idx < 4096; idx += 1024) {
        int v = n0 + (idx >> 4);
        if (v < NN) {
            int f = idx & 15;
            float sum = acc[idx] + g[v * 16 + f];  // + self loop
            out[v * 16 + f] = tanhf(dinv[v] * sum + bias[f]);
        }
    }
}

// g2[v][j] = (h1[v] . W2[:,j]) * dinv[v]
__global__ __launch_bounds__(256) void gemm2_kernel(const float* __restrict__ h1,
                                                    const float* __restrict__ dinv,
                                                    const float* __restrict__ W2,
                                                    float* __restrict__ g2) {
    __shared__ float w2l[16 * 16];
    __shared__ float ht[16 * 17];
    int tid = threadIdx.x;
    w2l[tid] = W2[tid];
    int n0 = blockIdx.x * 16;
    int ln = tid >> 4, j = tid & 15;
    int v = n0 + ln;
    ht[ln * 17 + j] = h1[v * 16 + j];
    __syncthreads();
    float a = 0.f;
#pragma unroll
    for (int k = 0; k < 16; ++k)
        a += ht[ln * 17 + k] * w2l[k * 16 + j];
    g2[v * 16 + j] = a * dinv[v];
}

extern "C" void kernel_launch(void* const* d_in, const int* in_sizes, int n_in,
                              void* d_out, int out_size, void* d_ws, size_t ws_size,
                              hipStream_t stream) {
    const float* x  = (const float*)d_in[0];
    const int*   ew = (const int*)d_in[1];
    const float* W1 = (const float*)d_in[2];
    const float* b1 = (const float*)d_in[3];
    const float* W2 = (const float*)d_in[4];
    const float* b2 = (const float*)d_in[5];
    float* out = (float*)d_out;
    char* ws = (char*)d_ws;

    unsigned int* flag    = (unsigned int*)(ws);
    unsigned int* gcursor = (unsigned int*)(ws + 1024);
    float* dinv = (float*)(ws + 65536);
    float* g    = (float*)(ws + 524288);
    unsigned int* pairs = (unsigned int*)(ws + 7340032);
    float* h1 = out;  // reuse d_out as the h1 buffer (rewritten by final prop)

    init_kernel<<<2, 256, 0, stream>>>(flag, gcursor);
    detect_kernel<<<1, 256, 0, stream>>>((const unsigned int*)ew, flag);
    bin_kernel<<<NBIN_BLK, 256, 0, stream>>>(ew, flag, gcursor, pairs);
    degdinv_kernel<<<NB, 256, 0, stream>>>(pairs, gcursor, dinv);
    gemm1_kernel<<<NN / 16, 256, 0, stream>>>(x, W1, dinv, g);
    prop_kernel<<<NB, 1024, 0, stream>>>(pairs, gcursor, g, dinv, b1, h1);
    gemm2_kernel<<<NN / 16, 256, 0, stream>>>(h1, dinv, W2, g);
    prop_kernel<<<NB, 1024, 0, stream>>>(pairs, gcursor, g, dinv, b2, out);
}